// Round 2
// baseline (478.205 us; speedup 1.0000x reference)
//
#include <hip/hip_runtime.h>

typedef unsigned short u16;
typedef __bf16 bf8_t __attribute__((ext_vector_type(8)));
typedef short short8 __attribute__((ext_vector_type(8)));
typedef float f32x4 __attribute__((ext_vector_type(4)));

#define DEV __device__ __forceinline__

DEV u16 f2bf(float x) {
  unsigned u = __builtin_bit_cast(unsigned, x);
  return (u16)((u + 0x7FFFu + ((u >> 16) & 1u)) >> 16);
}
DEV float bf2f(u16 x) {
  unsigned u = (unsigned)x << 16;
  return __builtin_bit_cast(float, u);
}

DEV void gload16(const u16* g, u16* l) {
  __builtin_amdgcn_global_load_lds((__attribute__((address_space(1))) void*)(g),
                                   (__attribute__((address_space(3))) void*)(l), 16, 0, 0);
}

#define BARRIER() do { asm volatile("" ::: "memory"); __builtin_amdgcn_s_barrier(); asm volatile("" ::: "memory"); } while (0)
#define VMCNT(n) asm volatile("s_waitcnt vmcnt(" #n ")" ::: "memory")
#define PRIO1 __builtin_amdgcn_s_setprio(1)
#define PRIO0 __builtin_amdgcn_s_setprio(0)

// ---------------- K0a: pointwise weights fp32 -> bf16, stacked [3*512][512] ----------------
__global__ void k_wconv(const float* __restrict__ f, const float* __restrict__ g,
                        const float* __restrict__ h, u16* __restrict__ out) {
  int i = blockIdx.x * 256 + threadIdx.x;   // 0..786431
  float v;
  if (i < 262144) v = f[i];
  else if (i < 524288) v = g[i - 262144];
  else v = h[i - 524288];
  out[i] = f2bf(v);
}

// ---------------- K0b: style [b][c][n] fp32 -> Xt [b][n][c] bf16 ----------------
__global__ __launch_bounds__(256) void k_xt(const float* __restrict__ style, u16* __restrict__ Xt) {
  __shared__ float t[32][33];
  int b = blockIdx.z, c0 = blockIdx.y * 32, n0 = blockIdx.x * 32;
  int tid = threadIdx.x, lr = tid >> 5, lc = tid & 31;
  const float* src = style + ((size_t)b * 512 + c0) * 4096 + n0;
#pragma unroll
  for (int it = 0; it < 4; ++it) {
    int r = it * 8 + lr;
    t[r][lc] = src[(size_t)r * 4096 + lc];
  }
  __syncthreads();
  u16* dst = Xt + ((size_t)b * 4096 + n0) * 512 + c0;
#pragma unroll
  for (int it = 0; it < 4; ++it) {
    int n = it * 8 + lr;
    dst[(size_t)n * 512 + lc] = f2bf(t[lc][n]);
  }
}

// ================= 256x256 8-phase branch GEMM =================
// C[b][1536][4096] = Wall[1536][512] @ Xt[b][4096][512]^T   (bf16 in/out, fp32 acc)
// 8 waves (2M x 4N), BK=64, double-buffered 128KiB LDS, global_load_lds staging
// with source-side XOR swizzle; counted vmcnt(4); setprio around MFMA quadrants.

// stage one half-tile (128 rows x 64 k) of an operand for K-tile kt into LDS slot.
// Global source is pre-swizzled: physical 16B chunk (r, cb) holds logical (r, cb ^ (r&7)).
DEV void stage_half(const u16* mat, int rc0, int kt, int half,
                    u16* ldsslot, int wave, int lane) {
  const u16* base = mat + (size_t)(rc0 + half * 128) * 512 + kt * 64;
  u16* ldsb = ldsslot + half * (128 * 64);
#pragma unroll
  for (int q = 0; q < 2; ++q) {
    int ci = (wave * 2 + q) * 64 + lane;   // 0..1023 16B-chunk id in half-tile
    int r = ci >> 3;
    int scb = (ci & 7) ^ (r & 7);
    gload16(base + (size_t)r * 512 + scb * 8, ldsb + (wave * 2 + q) * 512);
  }
}

// swizzled fragment read: logical (row, k = ks*32 + lkg*8 .. +7)
DEV bf8_t rdfrag(const u16* slot, int row, int ks, int lkg) {
  int off = (ks * 64 + lkg * 16) ^ ((row & 7) << 4);
  return *(const bf8_t*)((const char*)slot + row * 128 + off);
}

#define RD_A(dst, slot, mofs)                                     \
  _Pragma("unroll") for (int m = 0; m < 4; ++m)                   \
  _Pragma("unroll") for (int ks = 0; ks < 2; ++ks)                \
    dst[m][ks] = rdfrag(slot, wm * 128 + (mofs) + m * 16 + lrow, ks, lkg);

#define RD_B(dst, slot, nofs)                                     \
  _Pragma("unroll") for (int n = 0; n < 2; ++n)                   \
  _Pragma("unroll") for (int ks = 0; ks < 2; ++ks)                \
    dst[n][ks] = rdfrag(slot, wn * 64 + (nofs) + n * 16 + lrow, ks, lkg);

#define QUAD(AF, BF, MB, NB)                                                              \
  do {                                                                                    \
    _Pragma("unroll") for (int m = 0; m < 4; ++m)                                         \
    _Pragma("unroll") for (int n = 0; n < 2; ++n) {                                       \
      acc[(MB) + m][(NB) + n] = __builtin_amdgcn_mfma_f32_16x16x32_bf16(                  \
          AF[m][0], BF[n][0], acc[(MB) + m][(NB) + n], 0, 0, 0);                          \
      acc[(MB) + m][(NB) + n] = __builtin_amdgcn_mfma_f32_16x16x32_bf16(                  \
          AF[m][1], BF[n][1], acc[(MB) + m][(NB) + n], 0, 0, 0);                          \
    }                                                                                     \
  } while (0)

// 4 phases consuming one K-tile from (slotA, slotB); S0..S3 staged one per phase.
#define PHASES4(slotA, slotB, S0, S1, S2, S3, VMSTMT)   \
  RD_A(a0, slotA, 0);                                   \
  RD_B(b0, slotB, 0);                                   \
  S0;                                                   \
  BARRIER();                                            \
  PRIO1; QUAD(a0, b0, 0, 0); PRIO0;                     \
  BARRIER();                                            \
  RD_A(a1, slotA, 64);                                  \
  S1;                                                   \
  BARRIER();                                            \
  PRIO1; QUAD(a1, b0, 4, 0); PRIO0;                     \
  BARRIER();                                            \
  RD_B(b1, slotB, 32);                                  \
  S2;                                                   \
  BARRIER();                                            \
  PRIO1; QUAD(a0, b1, 0, 2); PRIO0;                     \
  BARRIER();                                            \
  S3;                                                   \
  BARRIER();                                            \
  PRIO1; QUAD(a1, b1, 4, 2); PRIO0;                     \
  VMSTMT;                                               \
  BARRIER();

__global__ __launch_bounds__(512, 2) void k_gemm256_branch(
    const u16* __restrict__ Wall, const u16* __restrict__ Xt, u16* __restrict__ Y) {
  // XCD-chunked swizzle: 1536 wg, 192 per XCD = exactly 2 batches per XCD L2.
  int bid = blockIdx.x;
  int wg = (bid & 7) * 192 + (bid >> 3);
  int b = wg / 96;
  int rr = wg % 96;
  int nt = rr / 6, mt = rr % 6;          // nt-outer: 6 consecutive wg share one B N-panel
  int M0 = mt * 256, N0 = nt * 256;
  const u16* A = Wall;                                  // [1536][512]
  const u16* B = Xt + (size_t)b * (4096 * 512);         // [4096][512]
  u16* C = Y + (size_t)b * (1536 * 4096);

  int tid = threadIdx.x, wave = tid >> 6, lane = tid & 63;
  int wm = wave >> 2, wn = wave & 3;
  int lrow = lane & 15, lkg = lane >> 4;

  __shared__ __align__(16) u16 lA[2][256 * 64];
  __shared__ __align__(16) u16 lB[2][256 * 64];

  f32x4 acc[8][4];
#pragma unroll
  for (int m = 0; m < 8; ++m)
#pragma unroll
    for (int n = 0; n < 4; ++n) acc[m][n] = (f32x4){0.f, 0.f, 0.f, 0.f};

  // prologue: tile0 A+B, tile1 A  (12 loads/wave); first 8 must land.
  stage_half(A, M0, 0, 0, lA[0], wave, lane);
  stage_half(A, M0, 0, 1, lA[0], wave, lane);
  stage_half(B, N0, 0, 0, lB[0], wave, lane);
  stage_half(B, N0, 0, 1, lB[0], wave, lane);
  stage_half(A, M0, 1, 0, lA[1], wave, lane);
  stage_half(A, M0, 1, 1, lA[1], wave, lane);
  VMCNT(4);
  BARRIER();

  bf8_t a0[4][2], a1[4][2], b0[2][2], b1[2][2];
#pragma unroll 1
  for (int it = 0; it < 4; ++it) {
    const int T = it * 2;
    const bool last = (it == 3);
    // ---- tile T (slot 0), phases 0-3 ----
    PHASES4(lA[0], lB[0],
            stage_half(B, N0, T + 1, 0, lB[1], wave, lane),
            stage_half(B, N0, T + 1, 1, lB[1], wave, lane),
            if (!last) stage_half(A, M0, T + 2, 0, lA[0], wave, lane),
            if (!last) stage_half(A, M0, T + 2, 1, lA[0], wave, lane),
            if (last) { VMCNT(0); } else { VMCNT(4); })
    // ---- tile T+1 (slot 1), phases 4-7 ----
    PHASES4(lA[1], lB[1],
            if (!last) stage_half(B, N0, T + 2, 0, lB[0], wave, lane),
            if (!last) stage_half(B, N0, T + 2, 1, lB[0], wave, lane),
            if (!last) stage_half(A, M0, T + 3, 0, lA[1], wave, lane),
            if (!last) stage_half(A, M0, T + 3, 1, lA[1], wave, lane),
            if (!last) { VMCNT(4); })
  }

  // epilogue: bf16 scatter store (same mapping as validated round-1 kernel)
  int orow = lkg * 4, ocol = lrow;
#pragma unroll
  for (int am = 0; am < 8; ++am)
#pragma unroll
    for (int an = 0; an < 4; ++an) {
      int row = M0 + wm * 128 + am * 16 + orow;
      int col = N0 + wn * 64 + an * 16 + ocol;
      u16* cp = C + (size_t)row * 4096 + col;
#pragma unroll
      for (int i = 0; i < 4; ++i) cp[(size_t)i * 4096] = f2bf(acc[am][an][i]);
    }
}

// ---------------- 128x128 GEMM helper (kept for final GEMM) ----------------
DEV void stage_tile(const u16* __restrict__ src, int row0, int kb,
                    u16* lds, int wave, int lane) {
#pragma unroll
  for (int qq = 0; qq < 2; ++qq) {
    int idx = (wave * 2 + qq) * 64 + lane;   // 0..511 16B-chunk id
    int r = idx >> 2;
    int cb = (idx & 3) * 8;
    gload16(src + (size_t)(row0 + r) * 512 + (kb + cb),
            lds + (wave * 2 + qq) * 512);
  }
}

// ---------------- K2: depthwise 3x3 dil-2 reflect-pad, in place on Y ----------------
// Y layout: [b][t*512+c][4096]
__global__ __launch_bounds__(256) void k_dw(u16* __restrict__ Y,
    const float* __restrict__ fwd, const float* __restrict__ gwd, const float* __restrict__ hwd) {
  int p = blockIdx.x;                 // b*1536 + t*512 + c
  int within = p % 1536;
  int t = within >> 9, c = within & 511;
  const float* wsrc = (t == 0) ? fwd : (t == 1) ? gwd : hwd;
  __shared__ float w[9];
  __shared__ float pl[4096];
  int tid = threadIdx.x;
  if (tid < 9) w[tid] = wsrc[c * 9 + tid];
  u16* plane = Y + (size_t)p * 4096;
#pragma unroll
  for (int qq = 0; qq < 2; ++qq) {
    int v = tid * 2 + qq;
    short8 d = *(const short8*)(plane + v * 8);
#pragma unroll
    for (int e = 0; e < 8; ++e) pl[v * 8 + e] = bf2f((u16)d[e]);
  }
  __syncthreads();
  int y = tid >> 2, xb = (tid & 3) * 16;
  float o[16];
#pragma unroll
  for (int e = 0; e < 16; ++e) o[e] = 0.f;
#pragma unroll
  for (int i = 0; i < 3; ++i) {
    int yy = y + 2 * i - 2;
    yy = yy < 0 ? -yy : (yy > 63 ? 126 - yy : yy);
    const float* row = pl + yy * 64;
#pragma unroll
    for (int j = 0; j < 3; ++j) {
      float wv = w[i * 3 + j];
#pragma unroll
      for (int e = 0; e < 16; ++e) {
        int xx = xb + e + 2 * j - 2;
        xx = xx < 0 ? -xx : (xx > 63 ? 126 - xx : xx);
        o[e] += wv * row[xx];
      }
    }
  }
  short8 s0, s1;
#pragma unroll
  for (int e = 0; e < 8; ++e) { s0[e] = (short)f2bf(o[e]); s1[e] = (short)f2bf(o[e + 8]); }
  *(short8*)(plane + y * 64 + xb) = s0;
  *(short8*)(plane + y * 64 + xb + 8) = s1;
}

// ---------------- K2b: v [c][n] -> Vt [b][n][c] (bf16) ----------------
__global__ __launch_bounds__(256) void k_vt(const u16* __restrict__ Y, u16* __restrict__ Vt) {
  __shared__ u16 tb[64][72];
  int b = blockIdx.z, c0 = blockIdx.y * 64, n0 = blockIdx.x * 64;
  int tid = threadIdx.x, r = tid >> 2, q = tid & 3;
  const u16* src = Y + ((size_t)b * 1536 + 1024 + c0) * 4096 + n0;  // t=2 -> v
  short8 d0 = *(const short8*)(src + (size_t)r * 4096 + q * 16);
  short8 d1 = *(const short8*)(src + (size_t)r * 4096 + q * 16 + 8);
#pragma unroll
  for (int e = 0; e < 8; ++e) { tb[r][q * 16 + e] = (u16)d0[e]; tb[r][q * 16 + 8 + e] = (u16)d1[e]; }
  __syncthreads();
  u16* dst = Vt + ((size_t)b * 4096 + n0) * 512 + c0;
  short8 s0, s1;
#pragma unroll
  for (int e = 0; e < 8; ++e) { s0[e] = (short)tb[q * 16 + e][r]; s1[e] = (short)tb[q * 16 + 8 + e][r]; }
  *(short8*)(dst + (size_t)r * 512 + q * 16) = s0;
  *(short8*)(dst + (size_t)r * 512 + q * 16 + 8) = s1;
}

// ---------------- K3a: energy partials E[part][b][h][64][64] = q@k^T ----------------
__global__ __launch_bounds__(256) void k_energy(const u16* __restrict__ Y, float* __restrict__ E) {
  int half = blockIdx.x, h = blockIdx.y, b = blockIdx.z;
  int tid = threadIdx.x, wave = tid >> 6, lane = tid & 63;
  const u16* q = Y + ((size_t)b * 1536 + h * 64) * 4096;          // t=0 -> q
  const u16* k = Y + ((size_t)b * 1536 + 512 + h * 64) * 4096;    // t=1 -> k
  f32x4 acc[4][4];
#pragma unroll
  for (int m = 0; m < 4; ++m)
#pragma unroll
    for (int n = 0; n < 4; ++n) acc[m][n] = (f32x4){0.f, 0.f, 0.f, 0.f};
  int lrow = lane & 15, lk = (lane >> 4) * 8;
  int nstart = half * 1024 + wave * 256;
#pragma unroll 1
  for (int it = 0; it < 8; ++it) {
    int nb = nstart + it * 32;
    bf8_t af[4], bff[4];
#pragma unroll
    for (int m = 0; m < 4; ++m)
      af[m] = *(const bf8_t*)(q + (size_t)(m * 16 + lrow) * 4096 + nb + lk);
#pragma unroll
    for (int n = 0; n < 4; ++n)
      bff[n] = *(const bf8_t*)(k + (size_t)(n * 16 + lrow) * 4096 + nb + lk);
#pragma unroll
    for (int m = 0; m < 4; ++m)
#pragma unroll
      for (int n = 0; n < 4; ++n)
        acc[m][n] = __builtin_amdgcn_mfma_f32_16x16x32_bf16(af[m], bff[n], acc[m][n], 0, 0, 0);
  }
  __shared__ float red[4][4096];
  int orow = (lane >> 4) * 4, ocol = lane & 15;
#pragma unroll
  for (int m = 0; m < 4; ++m)
#pragma unroll
    for (int n = 0; n < 4; ++n)
#pragma unroll
      for (int i = 0; i < 4; ++i)
        red[wave][(m * 16 + orow + i) * 64 + n * 16 + ocol] = acc[m][n][i];
  __syncthreads();
  float* Eo = E + ((size_t)(half * 16 + b) * 8 + h) * 4096;
  for (int v = tid; v < 4096; v += 256)
    Eo[v] = red[0][v] + red[1][v] + red[2][v] + red[3][v];
}

// ---------------- K3s: softmax over d (in place into part 0) ----------------
__global__ __launch_bounds__(64) void k_softmax(float* __restrict__ E, const float* __restrict__ temp) {
  int bh = blockIdx.x;          // b*8+h
  int b = bh >> 3, h = bh & 7;
  int c = threadIdx.x;
  float* p0 = E + (((size_t)b * 8 + h) * 64 + c) * 64;
  float tv = temp[h];
  float e[64];
  float mx = -1e30f;
#pragma unroll
  for (int d = 0; d < 64; ++d) {
    float v = (p0[d] + p0[d + 524288] + p0[d + 1048576] + p0[d + 1572864]) * tv;
    e[d] = v;
    mx = fmaxf(mx, v);
  }
  float s = 0.f;
#pragma unroll
  for (int d = 0; d < 64; ++d) { float v = __expf(e[d] - mx); e[d] = v; s += v; }
  float inv = 1.f / s;
#pragma unroll
  for (int d = 0; d < 64; ++d) p0[d] = e[d] * inv;
}

// ---------------- K3b: M2[b][o][h*64+d] = sum_cc ow[o][h*64+cc]*attn[b][h][cc][d] ----------------
__global__ __launch_bounds__(256) void k_m2(const float* __restrict__ E, const float* __restrict__ ow,
                                            u16* __restrict__ M2) {
  int og = blockIdx.x, h = blockIdx.y, b = blockIdx.z;
  __shared__ float at[4096];
  int tid = threadIdx.x;
  const float* attn = E + ((size_t)b * 8 + h) * 4096;
  for (int v = tid; v < 4096; v += 256) at[v] = attn[v];
  __syncthreads();
  int o = og * 64 + (tid >> 2), dq = (tid & 3) * 16;
  const float* owr = ow + (size_t)o * 512 + h * 64;
  float acc[16];
#pragma unroll
  for (int e = 0; e < 16; ++e) acc[e] = 0.f;
  for (int cc = 0; cc < 64; ++cc) {
    float wv = owr[cc];
#pragma unroll
    for (int e = 0; e < 16; ++e) acc[e] += wv * at[cc * 64 + dq + e];
  }
  u16* dst = M2 + ((size_t)b * 512 + o) * 512 + h * 64 + dq;
  short8 s0, s1;
#pragma unroll
  for (int e = 0; e < 8; ++e) { s0[e] = (short)f2bf(acc[e]); s1[e] = (short)f2bf(acc[e + 8]); }
  *(short8*)dst = s0;
  *(short8*)(dst + 8) = s1;
}

// ---------------- K4: out[b] = M2[b] @ v[b] + style[b]  (fp32 out) ----------------
// memory-bound (~328 MB); round-1 128^2 kernel kept unchanged.
__global__ __launch_bounds__(256, 2) void k_gemm_final(
    const u16* __restrict__ M2, const u16* __restrict__ Vt,
    const float* __restrict__ style, float* __restrict__ out) {
  int b = blockIdx.z;
  const u16* A = M2 + (size_t)b * (512 * 512);
  const u16* B = Vt + (size_t)b * (4096 * 512);
  const float* st = style + (size_t)b * (512 * 4096);
  float* op = out + (size_t)b * (512 * 4096);
  int M0 = blockIdx.y * 128, N0 = blockIdx.x * 128;
  int tid = threadIdx.x, wave = tid >> 6, lane = tid & 63;
  int wm = wave >> 1, wn = wave & 1;
  __shared__ __align__(16) u16 lA[2][128 * 32];
  __shared__ __align__(16) u16 lB[2][128 * 32];
  f32x4 acc[4][4];
#pragma unroll
  for (int m = 0; m < 4; ++m)
#pragma unroll
    for (int n = 0; n < 4; ++n) acc[m][n] = (f32x4){0.f, 0.f, 0.f, 0.f};
  stage_tile(A, M0, 0, &lA[0][0], wave, lane);
  stage_tile(B, N0, 0, &lB[0][0], wave, lane);
  __syncthreads();
  int lrow = lane & 15, lk = (lane >> 4) * 8;
#pragma unroll 2
  for (int kt = 0; kt < 16; ++kt) {
    int cur = kt & 1;
    if (kt < 15) {
      stage_tile(A, M0, (kt + 1) * 32, &lA[cur ^ 1][0], wave, lane);
      stage_tile(B, N0, (kt + 1) * 32, &lB[cur ^ 1][0], wave, lane);
    }
    bf8_t af[4], bff[4];
#pragma unroll
    for (int m = 0; m < 4; ++m)
      af[m] = *(const bf8_t*)&lA[cur][(wm * 64 + m * 16 + lrow) * 32 + lk];
#pragma unroll
    for (int n = 0; n < 4; ++n)
      bff[n] = *(const bf8_t*)&lB[cur][(wn * 64 + n * 16 + lrow) * 32 + lk];
#pragma unroll
    for (int m = 0; m < 4; ++m)
#pragma unroll
      for (int n = 0; n < 4; ++n)
        acc[m][n] = __builtin_amdgcn_mfma_f32_16x16x32_bf16(af[m], bff[n], acc[m][n], 0, 0, 0);
    __syncthreads();
  }
  int orow = (lane >> 4) * 4, ocol = lane & 15;
#pragma unroll
  for (int m = 0; m < 4; ++m)
#pragma unroll
    for (int n = 0; n < 4; ++n) {
      int row = M0 + wm * 64 + m * 16 + orow;
      int col = N0 + wn * 64 + n * 16 + ocol;
      float* cp = op + (size_t)row * 4096 + col;
      const float* sp = st + (size_t)row * 4096 + col;
#pragma unroll
      for (int i = 0; i < 4; ++i) cp[(size_t)i * 4096] = acc[m][n][i] + sp[(size_t)i * 4096];
    }
}

// ---------------- workspace layout (bytes) ----------------
// Wbf : [3*512][512] bf16             @ 0         (1.5 MB, rounded to 2 MB)
// Y   : [16][1536][4096] bf16         @ 2 MB      (192 MB)   q,k,v in place after k_dw
// Xt  : [16][4096][512] bf16          @ 203423744 (64 MB)    reused as Vt after K1
// E   : [4][16][8][64][64] f32        @ 270532608 (8 MB)     part0 becomes attn
// M2  : [16][512][512] bf16           @ 278921216 (8 MB)

extern "C" void kernel_launch(void* const* d_in, const int* in_sizes, int n_in,
                              void* d_out, int out_size, void* d_ws, size_t ws_size,
                              hipStream_t stream) {
  const float* style = (const float*)d_in[0];
  const float* fw1   = (const float*)d_in[1];
  const float* fwd_  = (const float*)d_in[2];
  const float* gw1   = (const float*)d_in[3];
  const float* gwd   = (const float*)d_in[4];
  const float* hw1   = (const float*)d_in[5];
  const float* hwd   = (const float*)d_in[6];
  const float* ow    = (const float*)d_in[7];
  const float* temp  = (const float*)d_in[8];
  float* out = (float*)d_out;

  char* ws = (char*)d_ws;
  u16*   Wbf = (u16*)(ws + 0);
  u16*   Y   = (u16*)(ws + (size_t)2097152);
  u16*   Xt  = (u16*)(ws + (size_t)203423744);
  u16*   Vt  = Xt;                         // reuse: Xt dead after GEMM, Vt born after k_dw
  float* E   = (float*)(ws + (size_t)270532608);
  u16*   M2  = (u16*)(ws + (size_t)278921216);

  k_wconv<<<3072, 256, 0, stream>>>(fw1, gw1, hw1, Wbf);
  k_xt<<<dim3(128, 16, 16), 256, 0, stream>>>(style, Xt);
  k_gemm256_branch<<<1536, 512, 0, stream>>>(Wbf, Xt, Y);
  k_dw<<<24576, 256, 0, stream>>>(Y, fwd_, gwd, hwd);
  k_vt<<<dim3(64, 8, 16), 256, 0, stream>>>(Y, Vt);
  k_energy<<<dim3(4, 8, 16), 256, 0, stream>>>(Y, E);
  k_softmax<<<128, 64, 0, stream>>>(E, temp);
  k_m2<<<dim3(8, 8, 16), 256, 0, stream>>>(E, ow, M2);
  k_gemm_final<<<dim3(32, 4, 16), 256, 0, stream>>>(M2, Vt, style, out);
}

// Round 4
// 408.369 us; speedup vs baseline: 1.1710x; 1.1710x over previous
//
#include <hip/hip_runtime.h>

typedef unsigned short u16;
typedef __bf16 bf8_t __attribute__((ext_vector_type(8)));
typedef short short8 __attribute__((ext_vector_type(8)));
typedef float f32x4 __attribute__((ext_vector_type(4)));

#define DEV __device__ __forceinline__

DEV u16 f2bf(float x) {
  unsigned u = __builtin_bit_cast(unsigned, x);
  return (u16)((u + 0x7FFFu + ((u >> 16) & 1u)) >> 16);
}
DEV float bf2f(u16 x) {
  unsigned u = (unsigned)x << 16;
  return __builtin_bit_cast(float, u);
}

DEV void gload16(const u16* g, u16* l) {
  __builtin_amdgcn_global_load_lds((__attribute__((address_space(1))) void*)(g),
                                   (__attribute__((address_space(3))) void*)(l), 16, 0, 0);
}

// ---------------- K0a: pointwise weights fp32 -> bf16, stacked [3*512][512] ----------------
__global__ void k_wconv(const float* __restrict__ f, const float* __restrict__ g,
                        const float* __restrict__ h, u16* __restrict__ out) {
  int i = blockIdx.x * 256 + threadIdx.x;   // 0..786431
  float v;
  if (i < 262144) v = f[i];
  else if (i < 524288) v = g[i - 262144];
  else v = h[i - 524288];
  out[i] = f2bf(v);
}

// ---------------- K0b: style [b][c][n] fp32 -> Xt [b][n][c] bf16 ----------------
__global__ __launch_bounds__(256) void k_xt(const float* __restrict__ style, u16* __restrict__ Xt) {
  __shared__ float t[32][33];
  int b = blockIdx.z, c0 = blockIdx.y * 32, n0 = blockIdx.x * 32;
  int tid = threadIdx.x, lr = tid >> 5, lc = tid & 31;
  const float* src = style + ((size_t)b * 512 + c0) * 4096 + n0;
#pragma unroll
  for (int it = 0; it < 4; ++it) {
    int r = it * 8 + lr;
    t[r][lc] = src[(size_t)r * 4096 + lc];
  }
  __syncthreads();
  u16* dst = Xt + ((size_t)b * 4096 + n0) * 512 + c0;
#pragma unroll
  for (int it = 0; it < 4; ++it) {
    int n = it * 8 + lr;
    dst[(size_t)n * 512 + lc] = f2bf(t[lc][n]);
  }
}

// ---------------- 128x128 GEMM staging helper (validated round-1 structure) ----------------
DEV void stage_tile(const u16* __restrict__ src, int row0, int kb,
                    u16* lds, int wave, int lane) {
#pragma unroll
  for (int qq = 0; qq < 2; ++qq) {
    int idx = (wave * 2 + qq) * 64 + lane;   // 0..511 16B-chunk id
    int r = idx >> 2;
    int cb = (idx & 3) * 8;
    gload16(src + (size_t)(row0 + r) * 512 + (kb + cb),
            lds + (wave * 2 + qq) * 512);    // wave-uniform base; HW adds lane*16B
  }
}

// ---------------- K1: Y[b][1536][4096] = Wall[1536][512] @ Xt[b][4096][512]^T ----------------
// round-1 validated 128^2 2-phase body; flat grid + bijective XCD-chunked swizzle
// (each XCD owns exactly 2 batches -> Xt[b] 4MB resident in its private L2).
__global__ __launch_bounds__(256, 2) void k_gemm_branch(
    const u16* __restrict__ Wall, const u16* __restrict__ Xt, u16* __restrict__ Y) {
  int bid = blockIdx.x;                     // 0..6143
  int xcd = bid & 7, idx = bid >> 3;        // idx 0..767
  int bh = idx / 384;                       // 0..1
  int r = idx - bh * 384;                   // 0..383
  int b = xcd * 2 + bh;
  int nt = r / 12, mt = r - nt * 12;        // 32 N-tiles, 12 M-tiles
  int M0 = mt * 128, N0 = nt * 128;
  const u16* A = Wall;                                  // [1536][512]
  const u16* B = Xt + (size_t)b * (4096 * 512);         // [4096][512]
  u16* C = Y + (size_t)b * (1536 * 4096);
  int tid = threadIdx.x, wave = tid >> 6, lane = tid & 63;
  int wm = wave >> 1, wn = wave & 1;
  __shared__ __align__(16) u16 lA[2][128 * 32];
  __shared__ __align__(16) u16 lB[2][128 * 32];
  f32x4 acc[4][4];
#pragma unroll
  for (int m = 0; m < 4; ++m)
#pragma unroll
    for (int n = 0; n < 4; ++n) acc[m][n] = (f32x4){0.f, 0.f, 0.f, 0.f};
  stage_tile(A, M0, 0, &lA[0][0], wave, lane);
  stage_tile(B, N0, 0, &lB[0][0], wave, lane);
  __syncthreads();
  int lrow = lane & 15, lk = (lane >> 4) * 8;
#pragma unroll 2
  for (int kt = 0; kt < 16; ++kt) {
    int cur = kt & 1;
    if (kt < 15) {
      stage_tile(A, M0, (kt + 1) * 32, &lA[cur ^ 1][0], wave, lane);
      stage_tile(B, N0, (kt + 1) * 32, &lB[cur ^ 1][0], wave, lane);
    }
    bf8_t af[4], bff[4];
#pragma unroll
    for (int m = 0; m < 4; ++m)
      af[m] = *(const bf8_t*)&lA[cur][(wm * 64 + m * 16 + lrow) * 32 + lk];
#pragma unroll
    for (int n = 0; n < 4; ++n)
      bff[n] = *(const bf8_t*)&lB[cur][(wn * 64 + n * 16 + lrow) * 32 + lk];
#pragma unroll
    for (int m = 0; m < 4; ++m)
#pragma unroll
      for (int n = 0; n < 4; ++n)
        acc[m][n] = __builtin_amdgcn_mfma_f32_16x16x32_bf16(af[m], bff[n], acc[m][n], 0, 0, 0);
    __syncthreads();
  }
  int orow = (lane >> 4) * 4, ocol = lane & 15;
#pragma unroll
  for (int m = 0; m < 4; ++m)
#pragma unroll
    for (int n = 0; n < 4; ++n) {
      int row = M0 + wm * 64 + m * 16 + orow;
      int col = N0 + wn * 64 + n * 16 + ocol;
      u16* cp = C + (size_t)row * 4096 + col;
#pragma unroll
      for (int i = 0; i < 4; ++i) cp[(size_t)i * 4096] = f2bf(acc[m][n][i]);
    }
}

// ---------------- fused depthwise row computation ----------------
// One image row (64 px) of depthwise 3x3 dil-2 with ReflectionPad2d(2), fp32.
// Reads 3 source rows (reflected) directly from the pre-dw global plane.
// Calls store(g, o) for 4 groups of 16 px; all indices compile-time.
template <typename F>
DEV void dw_row(const u16* plane, const float* w9, int y, F&& store) {
  short8 raw[3][8];
#pragma unroll
  for (int i = 0; i < 3; ++i) {
    int yy = y + 2 * i - 2;
    yy = yy < 0 ? -yy : (yy > 63 ? 126 - yy : yy);
    const short8* rp = (const short8*)(plane + yy * 64);
#pragma unroll
    for (int ch = 0; ch < 8; ++ch) raw[i][ch] = rp[ch];
  }
#pragma unroll
  for (int g = 0; g < 4; ++g) {
    float fr[3][20];
#pragma unroll
    for (int t = 0; t < 20; ++t) {
      int p = g * 16 - 2 + t;
      int rp2 = p < 0 ? -p : (p > 63 ? 126 - p : p);
#pragma unroll
      for (int i = 0; i < 3; ++i)
        fr[i][t] = bf2f((u16)raw[i][rp2 >> 3][rp2 & 7]);
    }
    float o[16];
#pragma unroll
    for (int e = 0; e < 16; ++e) {
      float s = 0.f;
#pragma unroll
      for (int i = 0; i < 3; ++i)
#pragma unroll
        for (int j = 0; j < 3; ++j)
          s += w9[i * 3 + j] * fr[i][e + 2 * j];
      o[e] = s;
    }
    store(g, o);
  }
}

// ---------------- K2: fused dw(q),dw(k) -> partial Gram E[band][b][h][64][64] ----------------
// Block = (band of 16 rows, h, b); 256 threads (4 waves). dw outputs staged in
// XOR-swizzled bf16 LDS tiles [64ch][256px]; MFMA accumulates E over 1024 px.
__global__ __launch_bounds__(256, 2) void k_dwE(const u16* __restrict__ Y,
    const float* __restrict__ fwd, const float* __restrict__ gwd, float* __restrict__ E) {
  int band = blockIdx.x, h = blockIdx.y, b = blockIdx.z;
  __shared__ __align__(16) u16 qbuf[64 * 256];
  __shared__ __align__(16) u16 kbuf[64 * 256];
  int tid = threadIdx.x;
  int c = ((tid >> 5) << 3) | (tid & 7);   // octets span c&7=0..7 -> conflict-free swizzled writes
  int yl = (tid >> 3) & 3;
  int wv = tid >> 6, lane = tid & 63;
  int lrow = lane & 15, lkg = lane >> 4;
  const u16* qp = Y + ((size_t)b * 1536 + h * 64 + c) * 4096;
  const u16* kp = Y + ((size_t)b * 1536 + 512 + h * 64 + c) * 4096;
  float wq9[9], wk9[9];
#pragma unroll
  for (int t = 0; t < 9; ++t) {
    wq9[t] = fwd[(h * 64 + c) * 9 + t];
    wk9[t] = gwd[(h * 64 + c) * 9 + t];
  }
  f32x4 acc[4];
#pragma unroll
  for (int n = 0; n < 4; ++n) acc[n] = (f32x4){0.f, 0.f, 0.f, 0.f};
  char* qrow = (char*)qbuf + c * 512;
  char* krow = (char*)kbuf + c * 512;
  int c7 = c & 7;
#pragma unroll 1
  for (int sb = 0; sb < 4; ++sb) {
    int y = band * 16 + sb * 4 + yl;
    dw_row(qp, wq9, y, [&](int g, const float* o) {
      short8 s0, s1;
#pragma unroll
      for (int e = 0; e < 8; ++e) { s0[e] = (short)f2bf(o[e]); s1[e] = (short)f2bf(o[e + 8]); }
      int ch0 = yl * 8 + g * 2;
      *(short8*)(qrow + 16 * (ch0 ^ c7)) = s0;
      *(short8*)(qrow + 16 * ((ch0 + 1) ^ c7)) = s1;
    });
    dw_row(kp, wk9, y, [&](int g, const float* o) {
      short8 s0, s1;
#pragma unroll
      for (int e = 0; e < 8; ++e) { s0[e] = (short)f2bf(o[e]); s1[e] = (short)f2bf(o[e + 8]); }
      int ch0 = yl * 8 + g * 2;
      *(short8*)(krow + 16 * (ch0 ^ c7)) = s0;
      *(short8*)(krow + 16 * ((ch0 + 1) ^ c7)) = s1;
    });
    __syncthreads();
    const char* qb = (const char*)qbuf + (wv * 16 + lrow) * 512;
    int ca7 = (wv * 16 + lrow) & 7;
#pragma unroll
    for (int ks = 0; ks < 8; ++ks) {
      bf8_t aF = *(const bf8_t*)(qb + 16 * ((ks * 4 + lkg) ^ ca7));
#pragma unroll
      for (int n = 0; n < 4; ++n) {
        int cb = n * 16 + lrow;
        bf8_t bF = *(const bf8_t*)((const char*)kbuf + cb * 512 + 16 * ((ks * 4 + lkg) ^ (cb & 7)));
        acc[n] = __builtin_amdgcn_mfma_f32_16x16x32_bf16(aF, bF, acc[n], 0, 0, 0);
      }
    }
    __syncthreads();
  }
  float* Eo = E + (((size_t)band * 16 + b) * 8 + h) * 4096;
  int orow = (lane >> 4) * 4, ocol = lane & 15;
#pragma unroll
  for (int n = 0; n < 4; ++n)
#pragma unroll
    for (int i = 0; i < 4; ++i)
      Eo[(wv * 16 + orow + i) * 64 + n * 16 + ocol] = acc[n][i];
}

// ---------------- K2b: fused dw(v) -> Vt[b][n][c] bf16 ----------------
// Block = (band of 16 rows, ctile of 64, b); LDS transpose [256 px][68 c] fp32.
__global__ __launch_bounds__(256, 2) void k_dwV(const u16* __restrict__ Y,
    const float* __restrict__ hwd, u16* __restrict__ Vt) {
  int band = blockIdx.x, ct = blockIdx.y, b = blockIdx.z;
  __shared__ float vb[256 * 68];
  int tid = threadIdx.x;
  int c = ((tid >> 5) << 3) | (tid & 7);
  int yl = (tid >> 3) & 3;
  int cg = tid & 7;
  int cglob = ct * 64 + c;
  const u16* plane = Y + ((size_t)b * 1536 + 1024 + cglob) * 4096;
  float w9[9];
#pragma unroll
  for (int t = 0; t < 9; ++t) w9[t] = hwd[cglob * 9 + t];
#pragma unroll 1
  for (int sb = 0; sb < 4; ++sb) {
    int y = band * 16 + sb * 4 + yl;
    dw_row(plane, w9, y, [&](int g, const float* o) {
#pragma unroll
      for (int e = 0; e < 16; ++e)
        vb[((g * 16 + e) * 4 + yl) * 68 + c] = o[e];   // n' = x*4+yl interleave
    });
    __syncthreads();
#pragma unroll
    for (int k = 0; k < 8; ++k) {
      int np = (tid >> 3) + 32 * k;            // n' 0..255
      int x = np >> 2, yy = np & 3;
      int ng = (band * 16 + sb * 4 + yy) * 64 + x;
      f32x4 r0 = *(const f32x4*)&vb[np * 68 + cg * 8];
      f32x4 r1 = *(const f32x4*)&vb[np * 68 + cg * 8 + 4];
      short8 s;
#pragma unroll
      for (int e = 0; e < 4; ++e) { s[e] = (short)f2bf(r0[e]); s[e + 4] = (short)f2bf(r1[e]); }
      *(short8*)(Vt + ((size_t)b * 4096 + ng) * 512 + ct * 64 + cg * 8) = s;
    }
    __syncthreads();
  }
}

// ---------------- K3s: softmax over d (4 partial bands summed; in place into part 0) ----------------
__global__ __launch_bounds__(64) void k_softmax(float* __restrict__ E, const float* __restrict__ temp) {
  int bh = blockIdx.x;          // b*8+h
  int b = bh >> 3, h = bh & 7;
  int c = threadIdx.x;
  float* p0 = E + (((size_t)b * 8 + h) * 64 + c) * 64;
  float tv = temp[h];
  float e[64];
  float mx = -1e30f;
#pragma unroll
  for (int d = 0; d < 64; ++d) {
    float v = (p0[d] + p0[d + 524288] + p0[d + 1048576] + p0[d + 1572864]) * tv;
    e[d] = v;
    mx = fmaxf(mx, v);
  }
  float s = 0.f;
#pragma unroll
  for (int d = 0; d < 64; ++d) { float v = __expf(e[d] - mx); e[d] = v; s += v; }
  float inv = 1.f / s;
#pragma unroll
  for (int d = 0; d < 64; ++d) p0[d] = e[d] * inv;
}

// ---------------- K3b: M2[b][o][h*64+d] = sum_cc ow[o][h*64+cc]*attn[b][h][cc][d] ----------------
__global__ __launch_bounds__(256) void k_m2(const float* __restrict__ E, const float* __restrict__ ow,
                                            u16* __restrict__ M2) {
  int og = blockIdx.x, h = blockIdx.y, b = blockIdx.z;
  __shared__ float at[4096];
  int tid = threadIdx.x;
  const float* attn = E + ((size_t)b * 8 + h) * 4096;
  for (int v = tid; v < 4096; v += 256) at[v] = attn[v];
  __syncthreads();
  int o = og * 64 + (tid >> 2), dq = (tid & 3) * 16;
  const float* owr = ow + (size_t)o * 512 + h * 64;
  float acc[16];
#pragma unroll
  for (int e = 0; e < 16; ++e) acc[e] = 0.f;
  for (int cc = 0; cc < 64; ++cc) {
    float wv = owr[cc];
#pragma unroll
    for (int e = 0; e < 16; ++e) acc[e] += wv * at[cc * 64 + dq + e];
  }
  u16* dst = M2 + ((size_t)b * 512 + o) * 512 + h * 64 + dq;
  short8 s0, s1;
#pragma unroll
  for (int e = 0; e < 8; ++e) { s0[e] = (short)f2bf(acc[e]); s1[e] = (short)f2bf(acc[e + 8]); }
  *(short8*)dst = s0;
  *(short8*)(dst + 8) = s1;
}

// ---------------- K4: out[b] = M2[b] @ v[b] + style[b]  (fp32 out; at memory floor) ----------------
__global__ __launch_bounds__(256, 2) void k_gemm_final(
    const u16* __restrict__ M2, const u16* __restrict__ Vt,
    const float* __restrict__ style, float* __restrict__ out) {
  int b = blockIdx.z;
  const u16* A = M2 + (size_t)b * (512 * 512);
  const u16* B = Vt + (size_t)b * (4096 * 512);
  const float* st = style + (size_t)b * (512 * 4096);
  float* op = out + (size_t)b * (512 * 4096);
  int M0 = blockIdx.y * 128, N0 = blockIdx.x * 128;
  int tid = threadIdx.x, wave = tid >> 6, lane = tid & 63;
  int wm = wave >> 1, wn = wave & 1;
  __shared__ __align__(16) u16 lA[2][128 * 32];
  __shared__ __align__(16) u16 lB[2][128 * 32];
  f32x4 acc[4][4];
#pragma unroll
  for (int m = 0; m < 4; ++m)
#pragma unroll
    for (int n = 0; n < 4; ++n) acc[m][n] = (f32x4){0.f, 0.f, 0.f, 0.f};
  stage_tile(A, M0, 0, &lA[0][0], wave, lane);
  stage_tile(B, N0, 0, &lB[0][0], wave, lane);
  __syncthreads();
  int lrow = lane & 15, lk = (lane >> 4) * 8;
#pragma unroll 2
  for (int kt = 0; kt < 16; ++kt) {
    int cur = kt & 1;
    if (kt < 15) {
      stage_tile(A, M0, (kt + 1) * 32, &lA[cur ^ 1][0], wave, lane);
      stage_tile(B, N0, (kt + 1) * 32, &lB[cur ^ 1][0], wave, lane);
    }
    bf8_t af[4], bff[4];
#pragma unroll
    for (int m = 0; m < 4; ++m)
      af[m] = *(const bf8_t*)&lA[cur][(wm * 64 + m * 16 + lrow) * 32 + lk];
#pragma unroll
    for (int n = 0; n < 4; ++n)
      bff[n] = *(const bf8_t*)&lB[cur][(wn * 64 + n * 16 + lrow) * 32 + lk];
#pragma unroll
    for (int m = 0; m < 4; ++m)
#pragma unroll
      for (int n = 0; n < 4; ++n)
        acc[m][n] = __builtin_amdgcn_mfma_f32_16x16x32_bf16(af[m], bff[n], acc[m][n], 0, 0, 0);
    __syncthreads();
  }
  int orow = (lane >> 4) * 4, ocol = lane & 15;
#pragma unroll
  for (int m = 0; m < 4; ++m)
#pragma unroll
    for (int n = 0; n < 4; ++n) {
      int row = M0 + wm * 64 + m * 16 + orow;
      int col = N0 + wn * 64 + n * 16 + ocol;
      float* cp = op + (size_t)row * 4096 + col;
      const float* sp = st + (size_t)row * 4096 + col;
#pragma unroll
      for (int i = 0; i < 4; ++i) cp[(size_t)i * 4096] = acc[m][n][i] + sp[(size_t)i * 4096];
    }
}

// ---------------- workspace layout (bytes) ----------------
// Wbf : [3*512][512] bf16             @ 0         (1.5 MB, rounded to 2 MB)
// Y   : [16][1536][4096] bf16         @ 2 MB      (192 MB)  PRE-dw q,k,v (never mutated)
// Xt  : [16][4096][512] bf16          @ 203423744 (64 MB)   reused as Vt after branch GEMM
// E   : [4][16][8][64][64] f32        @ 270532608 (8 MB)    part0 becomes attn
// M2  : [16][512][512] bf16           @ 278921216 (8 MB)

extern "C" void kernel_launch(void* const* d_in, const int* in_sizes, int n_in,
                              void* d_out, int out_size, void* d_ws, size_t ws_size,
                              hipStream_t stream) {
  const float* style = (const float*)d_in[0];
  const float* fw1   = (const float*)d_in[1];
  const float* fwd_  = (const float*)d_in[2];
  const float* gw1   = (const float*)d_in[3];
  const float* gwd   = (const float*)d_in[4];
  const float* hw1   = (const float*)d_in[5];
  const float* hwd   = (const float*)d_in[6];
  const float* ow    = (const float*)d_in[7];
  const float* temp  = (const float*)d_in[8];
  float* out = (float*)d_out;

  char* ws = (char*)d_ws;
  u16*   Wbf = (u16*)(ws + 0);
  u16*   Y   = (u16*)(ws + (size_t)2097152);
  u16*   Xt  = (u16*)(ws + (size_t)203423744);
  u16*   Vt  = Xt;                         // Xt dead after branch GEMM; Vt born in k_dwV
  float* E   = (float*)(ws + (size_t)270532608);
  u16*   M2  = (u16*)(ws + (size_t)278921216);

  k_wconv<<<3072, 256, 0, stream>>>(fw1, gw1, hw1, Wbf);
  k_xt<<<dim3(128, 16, 16), 256, 0, stream>>>(style, Xt);
  k_gemm_branch<<<6144, 256, 0, stream>>>(Wbf, Xt, Y);
  k_dwE<<<dim3(4, 8, 16), 256, 0, stream>>>(Y, fwd_, gwd, E);
  k_dwV<<<dim3(4, 8, 16), 256, 0, stream>>>(Y, hwd, Vt);
  k_softmax<<<128, 64, 0, stream>>>(E, temp);
  k_m2<<<dim3(8, 8, 16), 256, 0, stream>>>(E, ow, M2);
  k_gemm_final<<<dim3(32, 4, 16), 256, 0, stream>>>(M2, Vt, style, out);
}